// Round 2
// baseline (43.716 us; speedup 1.0000x reference)
//
#include <hip/hip_runtime.h>
#include <hip/hip_bf16.h>

typedef __attribute__((ext_vector_type(8))) short bf16x8;
typedef __attribute__((ext_vector_type(4))) float f32x4;
typedef unsigned short u16;
typedef unsigned int u32;

__device__ __forceinline__ u16 f2bf(float f) {
    u32 u = __builtin_bit_cast(u32, f);
    return (u16)((u + 0x7FFFu + ((u >> 16) & 1u)) >> 16);
}
__device__ __forceinline__ float sigm(float x) { return 1.f / (1.f + __expf(-x)); }
__device__ __forceinline__ float red16(float x) {
    x += __shfl_xor(x, 1, 64);
    x += __shfl_xor(x, 2, 64);
    x += __shfl_xor(x, 4, 64);
    x += __shfl_xor(x, 8, 64);
    return x;
}
__device__ __forceinline__ void gload_lds16(const void* g, void* l) {
    __builtin_amdgcn_global_load_lds((const __attribute__((address_space(1))) u32*)g,
                                     (__attribute__((address_space(3))) u32*)l, 16, 0, 0);
}

// ---------------- prep: fp32 W -> bf16 W in ws (6 x 256x256) -----------------
struct PrepArgs { const float* src[6]; u16* dst; };

__global__ __launch_bounds__(256) void prep_kernel(PrepArgs a) {
    int gid = blockIdx.x * 256 + threadIdx.x;       // 49152 threads, 8 elem each
    if (gid >= 49152) return;
    int w = gid >> 13;                               // which W (8192 thr per W)
    int off = (gid & 8191) * 8;
    const float* s = a.src[w] + off;
    f32x4 v0 = *(const f32x4*)s;
    f32x4 v1 = *(const f32x4*)(s + 4);
    uint4 o;
    o.x = (u32)f2bf(v0.x) | ((u32)f2bf(v0.y) << 16);
    o.y = (u32)f2bf(v0.z) | ((u32)f2bf(v0.w) << 16);
    o.z = (u32)f2bf(v1.x) | ((u32)f2bf(v1.y) << 16);
    o.w = (u32)f2bf(v1.z) | ((u32)f2bf(v1.w) << 16);
    *(uint4*)(a.dst + (size_t)gid * 8) = o;
}

// ---------------- fused: paired GEMM + LN + ReLU + interaction ---------------
// Block = (pair, mtile of 16 rows). 512 thr = 8 waves; wave w owns N cols
// [w*32, w*32+32) for BOTH gemms (G and P). Interaction is block-local.
struct PairTask {
    const float* xG; const float* xP;       // fp32 inputs [2048][256]
    const u16* WG;   const u16* WP;         // bf16 weights [256][256]
    const float *bG, *gmG, *beG;
    const float *bP, *gmP, *beP;
    const float *awG, *awP;                 // dot-weights: awG pairs with oG (apw), awP with oP (agw)
    const float *attbP, *attbG;             // scalar biases: apb, agb
    float* outG; float* outP;               // spec outputs; interact uses outG
    int interact;
};
struct FusedArgs { PairTask p[3]; };

__global__ __launch_bounds__(512) void fused_kernel(FusedArgs args) {
    // [2 gemms][256 rows][64 k] bf16 = 64 KB, XOR-swizzled via pre-swizzled source
    __shared__ u16 W_lds[512 * 64];
    // epilogue reductions aliased onto W_lds (safe: all W reads are behind the
    // final K-loop barrier before any epilogue write)
    float (*red_s)[16][8] = (float (*)[16][8])(W_lds);           // [g][row][wave]
    float (*red_q)[16][8] = (float (*)[16][8])(W_lds + 1024);
    float (*red_d)[16][8] = (float (*)[16][8])(W_lds + 2048);

    int wg = blockIdx.x;
    int swz = (wg & 7) * 48 + (wg >> 3);    // XCD-aware swizzle, 384 % 8 == 0
    int pair = swz >> 7;
    int mt = swz & 127;
    PairTask tk = args.p[pair];

    int tid = threadIdx.x;
    int wave = tid >> 6;
    int lane = tid & 63;
    int cq = lane & 15, rq = lane >> 4;

    // ---- A fragments: 16 rows, fp32 load + convert in-register (L1-shared) --
    bf16x8 aF[2][8];
    {
        int arow = mt * 16 + cq;
        const float* xg = tk.xG + (size_t)arow * 256 + rq * 8;
        const float* xp = tk.xP + (size_t)arow * 256 + rq * 8;
#pragma unroll
        for (int kc = 0; kc < 8; ++kc) {
            f32x4 a0 = *(const f32x4*)(xg + kc * 32);
            f32x4 a1 = *(const f32x4*)(xg + kc * 32 + 4);
            bf16x8 t;
            t[0] = (short)f2bf(a0.x); t[1] = (short)f2bf(a0.y);
            t[2] = (short)f2bf(a0.z); t[3] = (short)f2bf(a0.w);
            t[4] = (short)f2bf(a1.x); t[5] = (short)f2bf(a1.y);
            t[6] = (short)f2bf(a1.z); t[7] = (short)f2bf(a1.w);
            aF[0][kc] = t;
            f32x4 p0 = *(const f32x4*)(xp + kc * 32);
            f32x4 p1 = *(const f32x4*)(xp + kc * 32 + 4);
            bf16x8 u;
            u[0] = (short)f2bf(p0.x); u[1] = (short)f2bf(p0.y);
            u[2] = (short)f2bf(p0.z); u[3] = (short)f2bf(p0.w);
            u[4] = (short)f2bf(p1.x); u[5] = (short)f2bf(p1.y);
            u[6] = (short)f2bf(p1.z); u[7] = (short)f2bf(p1.w);
            aF[1][kc] = u;
        }
    }

    f32x4 acc[2][2];
#pragma unroll
    for (int g = 0; g < 2; ++g)
#pragma unroll
        for (int nt = 0; nt < 2; ++nt) acc[g][nt] = (f32x4){0.f, 0.f, 0.f, 0.f};

    // source-side swizzle so linear global_load_lds lands data such that the
    // swizzled ds_read below is conflict-free: chunk c16 of row r holds
    // global chunk (c16 ^ (r&7))
    const int swz16 = ((lane & 7) ^ (lane >> 3)) * 16;

#pragma unroll
    for (int kt = 0; kt < 4; ++kt) {
        // stage 64KB: [512 rows][128B] via global_load_lds dwordx4
#pragma unroll
        for (int i = 0; i < 8; ++i) {
            int rb = (i * 8 + wave) * 8;            // wave-uniform row base
            int rr = rb + (lane >> 3);
            const u16* wsrc = (rb < 256) ? (tk.WG + (size_t)rr * 256)
                                         : (tk.WP + (size_t)(rr - 256) * 256);
            const char* gsrc = (const char*)wsrc + kt * 128 + swz16;
            char* ldsb = (char*)W_lds + (i * 8 + wave) * 1024;   // + lane*16 by HW
            gload_lds16(gsrc, ldsb);
        }
        __syncthreads();
#pragma unroll
        for (int kk = 0; kk < 2; ++kk) {
#pragma unroll
            for (int g = 0; g < 2; ++g) {
#pragma unroll
                for (int nt = 0; nt < 2; ++nt) {
                    int n = wave * 32 + nt * 16 + cq;
                    int logical = (kk * 32 + rq * 8) * 2;        // byte in 128B row
                    int addr = g * 32768 + n * 128 + (logical ^ ((n & 7) << 4));
                    bf16x8 b = *(const bf16x8*)((const char*)W_lds + addr);
                    acc[g][nt] = __builtin_amdgcn_mfma_f32_16x16x32_bf16(
                        aF[g][kt * 2 + kk], b, acc[g][nt], 0, 0, 0);
                }
            }
        }
        __syncthreads();
    }

    // ---------------------------- epilogue -----------------------------------
    float bb[2][2], gm[2][2], be[2][2], aw[2][2];
#pragma unroll
    for (int g = 0; g < 2; ++g)
#pragma unroll
        for (int nt = 0; nt < 2; ++nt) {
            int c = wave * 32 + nt * 16 + cq;
            bb[g][nt] = g ? tk.bP[c] : tk.bG[c];
            gm[g][nt] = g ? tk.gmP[c] : tk.gmG[c];
            be[g][nt] = g ? tk.beP[c] : tk.beG[c];
            aw[g][nt] = tk.interact ? (g ? tk.awP[c] : tk.awG[c]) : 0.f;
        }

    float v[2][2][4];
#pragma unroll
    for (int r = 0; r < 4; ++r) {
#pragma unroll
        for (int g = 0; g < 2; ++g) {
            float s = 0.f, q = 0.f;
#pragma unroll
            for (int nt = 0; nt < 2; ++nt) {
                float t = acc[g][nt][r] + bb[g][nt];
                v[g][nt][r] = t;
                s += t; q += t * t;
            }
            s = red16(s); q = red16(q);
            if (cq == 0) {
                int row = rq * 4 + r;
                red_s[g][row][wave] = s;
                red_q[g][row][wave] = q;
            }
        }
    }
    __syncthreads();

    float o[2][2][4];
#pragma unroll
    for (int r = 0; r < 4; ++r) {
        int row = rq * 4 + r;
#pragma unroll
        for (int g = 0; g < 2; ++g) {
            f32x4 s0 = *(const f32x4*)&red_s[g][row][0];
            f32x4 s1 = *(const f32x4*)&red_s[g][row][4];
            f32x4 q0 = *(const f32x4*)&red_q[g][row][0];
            f32x4 q1 = *(const f32x4*)&red_q[g][row][4];
            float s = s0.x + s0.y + s0.z + s0.w + s1.x + s1.y + s1.z + s1.w;
            float q = q0.x + q0.y + q0.z + q0.w + q1.x + q1.y + q1.z + q1.w;
            float mean = s * (1.f / 256.f);
            float var = q * (1.f / 256.f) - mean * mean;
            float rstd = rsqrtf(var + 1e-5f);
#pragma unroll
            for (int nt = 0; nt < 2; ++nt)
                o[g][nt][r] = fmaxf((v[g][nt][r] - mean) * rstd * gm[g][nt] + be[g][nt], 0.f);
        }
    }

    if (!tk.interact) {
#pragma unroll
        for (int r = 0; r < 4; ++r) {
            int grow = mt * 16 + rq * 4 + r;
#pragma unroll
            for (int nt = 0; nt < 2; ++nt) {
                int c = wave * 32 + nt * 16 + cq;
                tk.outG[(size_t)grow * 256 + c] = o[0][nt][r];
                tk.outP[(size_t)grow * 256 + c] = o[1][nt][r];
            }
        }
    } else {
        float battP = *tk.attbP, battG = *tk.attbG;
#pragma unroll
        for (int r = 0; r < 4; ++r) {
            float dg = 0.f, dp = 0.f;
#pragma unroll
            for (int nt = 0; nt < 2; ++nt) {
                dg += o[0][nt][r] * aw[0][nt];
                dp += o[1][nt][r] * aw[1][nt];
            }
            dg = red16(dg); dp = red16(dp);
            if (cq == 0) {
                int row = rq * 4 + r;
                red_d[0][row][wave] = dg;
                red_d[1][row][wave] = dp;
            }
        }
        __syncthreads();
#pragma unroll
        for (int r = 0; r < 4; ++r) {
            int row = rq * 4 + r;
            f32x4 d0 = *(const f32x4*)&red_d[0][row][0];
            f32x4 d1 = *(const f32x4*)&red_d[0][row][4];
            f32x4 e0 = *(const f32x4*)&red_d[1][row][0];
            f32x4 e1 = *(const f32x4*)&red_d[1][row][4];
            float dG = d0.x + d0.y + d0.z + d0.w + d1.x + d1.y + d1.z + d1.w;
            float dP = e0.x + e0.y + e0.z + e0.w + e1.x + e1.y + e1.z + e1.w;
            int grow = mt * 16 + row;
#pragma unroll
            for (int nt = 0; nt < 2; ++nt) {
                int c = wave * 32 + nt * 16 + cq;
                float og = o[0][nt][r], op = o[1][nt][r];
                tk.outG[(size_t)grow * 256 + c] =
                    op * sigm(op * dG + battP) + og * sigm(og * dP + battG);
            }
        }
    }
}

// -----------------------------------------------------------------------------
extern "C" void kernel_launch(void* const* d_in, const int* in_sizes, int n_in,
                              void* d_out, int out_size, void* d_ws, size_t ws_size,
                              hipStream_t stream) {
    const float* gfeat = (const float*)d_in[0];
    const float* pfeat = (const float*)d_in[1];
    float* out = (float*)d_out;
    u16* wbf = (u16*)d_ws;
    const size_t S = (size_t)2048 * 256;

    float* out_common = out + 0 * S;
    float* out_syn    = out + 1 * S;
    float* out_gspec  = out + 2 * S;
    float* out_pspec  = out + 3 * S;

    PrepArgs pa;
    pa.src[0] = (const float*)d_in[2];    // gs_W
    pa.src[1] = (const float*)d_in[6];    // ps_W
    pa.src[2] = (const float*)d_in[10];   // c_g_W
    pa.src[3] = (const float*)d_in[14];   // c_p_W
    pa.src[4] = (const float*)d_in[22];   // s_g_W
    pa.src[5] = (const float*)d_in[26];   // s_p_W
    pa.dst = wbf;
    hipLaunchKernelGGL(prep_kernel, dim3(192), dim3(256), 0, stream, pa);

    const u16* W0 = wbf;
    const u16* W1 = wbf + 1 * 65536;
    const u16* W2 = wbf + 2 * 65536;
    const u16* W3 = wbf + 3 * 65536;
    const u16* W4 = wbf + 4 * 65536;
    const u16* W5 = wbf + 5 * 65536;

    FusedArgs fa;
    // pair 0: spec — G: mlp(gfeat, gs_*) -> g_spec ; P: mlp(pfeat, ps_*) -> p_spec
    fa.p[0] = { gfeat, pfeat, W0, W1,
                (const float*)d_in[3], (const float*)d_in[4], (const float*)d_in[5],
                (const float*)d_in[7], (const float*)d_in[8], (const float*)d_in[9],
                nullptr, nullptr, nullptr, nullptr,
                out_gspec, out_pspec, 0 };
    // pair 1: common — G: mlp(pfeat, c_g_*), P: mlp(gfeat, c_p_*)
    fa.p[1] = { pfeat, gfeat, W2, W3,
                (const float*)d_in[11], (const float*)d_in[12], (const float*)d_in[13],
                (const float*)d_in[15], (const float*)d_in[16], (const float*)d_in[17],
                (const float*)d_in[20] /*c_apw*/, (const float*)d_in[18] /*c_agw*/,
                (const float*)d_in[21] /*c_apb*/, (const float*)d_in[19] /*c_agb*/,
                out_common, nullptr, 1 };
    // pair 2: synergy — G: mlp(pfeat, s_g_*), P: mlp(gfeat, s_p_*)
    fa.p[2] = { pfeat, gfeat, W4, W5,
                (const float*)d_in[23], (const float*)d_in[24], (const float*)d_in[25],
                (const float*)d_in[27], (const float*)d_in[28], (const float*)d_in[29],
                (const float*)d_in[32] /*s_apw*/, (const float*)d_in[30] /*s_agw*/,
                (const float*)d_in[33] /*s_apb*/, (const float*)d_in[31] /*s_agb*/,
                out_syn, nullptr, 1 };

    hipLaunchKernelGGL(fused_kernel, dim3(384), dim3(512), 0, stream, fa);
}

// Round 3
// 23.282 us; speedup vs baseline: 1.8777x; 1.8777x over previous
//
#include <hip/hip_runtime.h>

typedef __attribute__((ext_vector_type(8))) short bf16x8;
typedef __attribute__((ext_vector_type(4))) float f32x4;
typedef unsigned short u16;
typedef unsigned int u32;

__device__ __forceinline__ u16 f2bf(float f) {
    u32 u = __builtin_bit_cast(u32, f);
    return (u16)((u + 0x7FFFu + ((u >> 16) & 1u)) >> 16);
}
__device__ __forceinline__ float sigm(float x) { return 1.f / (1.f + __expf(-x)); }
__device__ __forceinline__ float red16(float x) {
    x += __shfl_xor(x, 1, 64);
    x += __shfl_xor(x, 2, 64);
    x += __shfl_xor(x, 4, 64);
    x += __shfl_xor(x, 8, 64);
    return x;
}
__device__ __forceinline__ uint4 pack8(const float* s) {
    f32x4 v0 = *(const f32x4*)s;
    f32x4 v1 = *(const f32x4*)(s + 4);
    uint4 o;
    o.x = (u32)f2bf(v0.x) | ((u32)f2bf(v0.y) << 16);
    o.y = (u32)f2bf(v0.z) | ((u32)f2bf(v0.w) << 16);
    o.z = (u32)f2bf(v1.x) | ((u32)f2bf(v1.y) << 16);
    o.w = (u32)f2bf(v1.z) | ((u32)f2bf(v1.w) << 16);
    return o;
}

// ---------------- prep: fp32 -> bf16 in MFMA-fragment order ------------------
// wf layout: [mlp6][wave4][nt4][kk8][lane64][8]   (65536 u16 per mlp)
// xf layout: [tensor2][mt128][kk8][lane64][8]     (524288 u16 per tensor)
struct PrepArgs { const float* W[6]; const float* xg; const float* xp; u16* wf; u16* xf; };

__global__ __launch_bounds__(256) void prep_kernel(PrepArgs a) {
    int gid = blockIdx.x * 256 + threadIdx.x;
    if (gid < 49152) {
        int l = gid & 63, kk = (gid >> 6) & 7, nt = (gid >> 9) & 3,
            w = (gid >> 11) & 3, mlp = gid >> 13;
        int n = w * 64 + nt * 16 + (l & 15);
        int k0 = kk * 32 + (l >> 4) * 8;
        *(uint4*)(a.wf + (size_t)gid * 8) = pack8(a.W[mlp] + n * 256 + k0);
    } else if (gid < 49152 + 131072) {
        int r = gid - 49152;
        const float* x = (r >> 16) ? a.xp : a.xg;
        int q = r & 65535;
        int l = q & 63, kk = (q >> 6) & 7, mt = q >> 9;
        int row = mt * 16 + (l & 15);
        int k0 = kk * 32 + (l >> 4) * 8;
        *(uint4*)(a.xf + (size_t)r * 8) = pack8(x + row * 256 + k0);
    }
}

// ---------------- fused: paired GEMM + LN + ReLU + interaction ---------------
// 256 thr = 4 waves; wave w owns N cols [w*64, w*64+64) for BOTH gemms.
// No LDS / no barriers in the main loop; B-frags stream from L2.
struct PairTask {
    const u16 *xfG, *xfP;                   // A-frag tensors [128][8][64][8]
    const u16 *WG, *WP;                     // B-frag tensors [4][4][8][64][8]
    const float *bG, *gmG, *beG;
    const float *bP, *gmP, *beP;
    const float *awG, *awP;                 // awG=apw pairs with oG; awP=agw with oP
    const float *attbP, *attbG;             // apb, agb
    float* outG; float* outP;
    int interact;
};
struct FusedArgs { PairTask p[3]; };

__global__ __launch_bounds__(256) void fused_kernel(FusedArgs args) {
    __shared__ float red_s[2][16][4];
    __shared__ float red_q[2][16][4];
    __shared__ float red_d[2][16][4];

    int wg = blockIdx.x;
    int swz = (wg & 7) * 48 + (wg >> 3);    // XCD swizzle, 384 % 8 == 0, bijective
    int pair = swz >> 7;
    int mt = swz & 127;
    PairTask tk = args.p[pair];

    int tid = threadIdx.x;
    int wave = tid >> 6;
    int lane = tid & 63;
    int cq = lane & 15, rq = lane >> 4;

    // ---- A fragments: 16 coalesced 16B/lane loads --------------------------
    bf16x8 aF[2][8];
#pragma unroll
    for (int kk = 0; kk < 8; ++kk) {
        aF[0][kk] = *(const bf16x8*)(tk.xfG + ((size_t)(mt * 8 + kk) * 64 + lane) * 8);
        aF[1][kk] = *(const bf16x8*)(tk.xfP + ((size_t)(mt * 8 + kk) * 64 + lane) * 8);
    }

    f32x4 acc[2][4];
#pragma unroll
    for (int g = 0; g < 2; ++g)
#pragma unroll
        for (int nt = 0; nt < 4; ++nt) acc[g][nt] = (f32x4){0.f, 0.f, 0.f, 0.f};

    const u16* wb0 = tk.WG + (size_t)wave * 16384 + lane * 8;
    const u16* wb1 = tk.WP + (size_t)wave * 16384 + lane * 8;

    // ---- main loop: 64 independent B loads + 64 MFMAs, no barriers ---------
#pragma unroll
    for (int kk = 0; kk < 8; ++kk) {
#pragma unroll
        for (int nt = 0; nt < 4; ++nt) {
            bf16x8 b0 = *(const bf16x8*)(wb0 + (size_t)(nt * 8 + kk) * 512);
            acc[0][nt] = __builtin_amdgcn_mfma_f32_16x16x32_bf16(aF[0][kk], b0, acc[0][nt], 0, 0, 0);
            bf16x8 b1 = *(const bf16x8*)(wb1 + (size_t)(nt * 8 + kk) * 512);
            acc[1][nt] = __builtin_amdgcn_mfma_f32_16x16x32_bf16(aF[1][kk], b1, acc[1][nt], 0, 0, 0);
        }
    }

    // ---------------------------- epilogue ----------------------------------
    float bb[2][4], gm[2][4], be[2][4], aw[2][4];
#pragma unroll
    for (int g = 0; g < 2; ++g)
#pragma unroll
        for (int nt = 0; nt < 4; ++nt) {
            int c = wave * 64 + nt * 16 + cq;
            bb[g][nt] = g ? tk.bP[c] : tk.bG[c];
            gm[g][nt] = g ? tk.gmP[c] : tk.gmG[c];
            be[g][nt] = g ? tk.beP[c] : tk.beG[c];
            aw[g][nt] = tk.interact ? (g ? tk.awP[c] : tk.awG[c]) : 0.f;
        }

    float v[2][4][4];
#pragma unroll
    for (int r = 0; r < 4; ++r) {
#pragma unroll
        for (int g = 0; g < 2; ++g) {
            float s = 0.f, q = 0.f;
#pragma unroll
            for (int nt = 0; nt < 4; ++nt) {
                float t = acc[g][nt][r] + bb[g][nt];
                v[g][nt][r] = t;
                s += t; q += t * t;
            }
            s = red16(s); q = red16(q);
            if (cq == 0) {
                red_s[g][rq * 4 + r][wave] = s;
                red_q[g][rq * 4 + r][wave] = q;
            }
        }
    }
    __syncthreads();

    float o[2][4][4];
#pragma unroll
    for (int r = 0; r < 4; ++r) {
        int row = rq * 4 + r;
#pragma unroll
        for (int g = 0; g < 2; ++g) {
            f32x4 s4 = *(const f32x4*)&red_s[g][row][0];
            f32x4 q4 = *(const f32x4*)&red_q[g][row][0];
            float s = s4.x + s4.y + s4.z + s4.w;
            float q = q4.x + q4.y + q4.z + q4.w;
            float mean = s * (1.f / 256.f);
            float var = q * (1.f / 256.f) - mean * mean;
            float rstd = rsqrtf(var + 1e-5f);
#pragma unroll
            for (int nt = 0; nt < 4; ++nt)
                o[g][nt][r] = fmaxf((v[g][nt][r] - mean) * rstd * gm[g][nt] + be[g][nt], 0.f);
        }
    }

    if (!tk.interact) {
#pragma unroll
        for (int r = 0; r < 4; ++r) {
            int grow = mt * 16 + rq * 4 + r;
#pragma unroll
            for (int nt = 0; nt < 4; ++nt) {
                int c = wave * 64 + nt * 16 + cq;
                tk.outG[(size_t)grow * 256 + c] = o[0][nt][r];
                tk.outP[(size_t)grow * 256 + c] = o[1][nt][r];
            }
        }
    } else {
        float battP = *tk.attbP, battG = *tk.attbG;
#pragma unroll
        for (int r = 0; r < 4; ++r) {
            float dg = 0.f, dp = 0.f;
#pragma unroll
            for (int nt = 0; nt < 4; ++nt) {
                dg += o[0][nt][r] * aw[0][nt];
                dp += o[1][nt][r] * aw[1][nt];
            }
            dg = red16(dg); dp = red16(dp);
            if (cq == 0) {
                red_d[0][rq * 4 + r][wave] = dg;
                red_d[1][rq * 4 + r][wave] = dp;
            }
        }
        __syncthreads();
#pragma unroll
        for (int r = 0; r < 4; ++r) {
            int row = rq * 4 + r;
            f32x4 d4 = *(const f32x4*)&red_d[0][row][0];
            f32x4 e4 = *(const f32x4*)&red_d[1][row][0];
            float dG = d4.x + d4.y + d4.z + d4.w;   // dot(g_align, apw)
            float dP = e4.x + e4.y + e4.z + e4.w;   // dot(p_align, agw)
            int grow = mt * 16 + row;
#pragma unroll
            for (int nt = 0; nt < 4; ++nt) {
                int c = wave * 64 + nt * 16 + cq;
                float og = o[0][nt][r], op = o[1][nt][r];
                tk.outG[(size_t)grow * 256 + c] =
                    op * sigm(op * dG + battP) + og * sigm(og * dP + battG);
            }
        }
    }
}

// -----------------------------------------------------------------------------
extern "C" void kernel_launch(void* const* d_in, const int* in_sizes, int n_in,
                              void* d_out, int out_size, void* d_ws, size_t ws_size,
                              hipStream_t stream) {
    const float* gfeat = (const float*)d_in[0];
    const float* pfeat = (const float*)d_in[1];
    float* out = (float*)d_out;
    const size_t S = (size_t)2048 * 256;

    float* out_common = out + 0 * S;
    float* out_syn    = out + 1 * S;
    float* out_gspec  = out + 2 * S;
    float* out_pspec  = out + 3 * S;

    u16* wf = (u16*)d_ws;                   // 6 * 65536 u16
    u16* xf = wf + 6 * 65536;               // 2 * 524288 u16
    u16* xf_g = xf;
    u16* xf_p = xf + 524288;

    PrepArgs pa;
    pa.W[0] = (const float*)d_in[2];    // gs_W
    pa.W[1] = (const float*)d_in[6];    // ps_W
    pa.W[2] = (const float*)d_in[10];   // c_g_W
    pa.W[3] = (const float*)d_in[14];   // c_p_W
    pa.W[4] = (const float*)d_in[22];   // s_g_W
    pa.W[5] = (const float*)d_in[26];   // s_p_W
    pa.xg = gfeat; pa.xp = pfeat;
    pa.wf = wf; pa.xf = xf;
    hipLaunchKernelGGL(prep_kernel, dim3(704), dim3(256), 0, stream, pa);

    FusedArgs fa;
    // pair 0: spec — G: mlp(gfeat, gs_*) -> g_spec ; P: mlp(pfeat, ps_*) -> p_spec
    fa.p[0] = { xf_g, xf_p, wf + 0 * 65536, wf + 1 * 65536,
                (const float*)d_in[3], (const float*)d_in[4], (const float*)d_in[5],
                (const float*)d_in[7], (const float*)d_in[8], (const float*)d_in[9],
                nullptr, nullptr, nullptr, nullptr,
                out_gspec, out_pspec, 0 };
    // pair 1: common — G: mlp(pfeat, c_g_*), P: mlp(gfeat, c_p_*)
    fa.p[1] = { xf_p, xf_g, wf + 2 * 65536, wf + 3 * 65536,
                (const float*)d_in[11], (const float*)d_in[12], (const float*)d_in[13],
                (const float*)d_in[15], (const float*)d_in[16], (const float*)d_in[17],
                (const float*)d_in[20] /*c_apw*/, (const float*)d_in[18] /*c_agw*/,
                (const float*)d_in[21] /*c_apb*/, (const float*)d_in[19] /*c_agb*/,
                out_common, nullptr, 1 };
    // pair 2: synergy — G: mlp(pfeat, s_g_*), P: mlp(gfeat, s_p_*)
    fa.p[2] = { xf_p, xf_g, wf + 4 * 65536, wf + 5 * 65536,
                (const float*)d_in[23], (const float*)d_in[24], (const float*)d_in[25],
                (const float*)d_in[27], (const float*)d_in[28], (const float*)d_in[29],
                (const float*)d_in[32] /*s_apw*/, (const float*)d_in[30] /*s_agw*/,
                (const float*)d_in[33] /*s_apb*/, (const float*)d_in[31] /*s_agb*/,
                out_syn, nullptr, 1 };

    hipLaunchKernelGGL(fused_kernel, dim3(384), dim3(256), 0, stream, fa);
}